// Round 1
// baseline (4748.257 us; speedup 1.0000x reference)
//
#include <hip/hip_runtime.h>
#include <hip/hip_bf16.h>

typedef __hip_bfloat16 hb;
typedef __bf16 bf16x8 __attribute__((ext_vector_type(8)));
typedef float f32x4 __attribute__((ext_vector_type(4)));

#define N_DEPTH 6
#define N_DIM   512
#define N_HEADS 8
#define N_MLP   2048
#define N_TOK   197
#define N_PATCH 196
#define N_BATCH 64
#define ROWS    (N_BATCH * N_TOK)     /* 12608 */
#define ROWS_PAD 12672                /* 99 * 128 */
#define PROWS   (N_BATCH * N_PATCH)   /* 12544 = 98 * 128 */

// ---------------- workspace layout (bytes) ----------------
#define OFF_WPATCH 0u
#define OFF_WQKV   786432u
#define OFF_WOUT   10223616u
#define OFF_WFC1   13369344u
#define OFF_WFC2   25952256u
#define OFF_XBF    38535168u
#define OFF_CTX    51511296u
#define OFF_BIG    64487424u      /* shared slot: Xp / qkv / h_mlp (51,904,512 B) */
#define OFF_XF     116391936u
#define OFF_H1     142344192u
/* total 168,296,448 B */

// ---------------- small utility kernels ----------------

__global__ void cvt_bf16_kernel(const float* __restrict__ in, hb* __restrict__ out, int n) {
    int t = blockIdx.x * 256 + threadIdx.x;
    if (t < n) out[t] = __float2bfloat16(in[t]);
}

// Xp[r][j]: r = b*196 + ph*14 + pw ; j = p1*48 + p2*3 + c ; pixel img[b,c,ph*16+p1,pw*16+p2]
__global__ void patchify_kernel(const float* __restrict__ img, hb* __restrict__ Xp) {
    int t = blockIdx.x * 256 + threadIdx.x;
    if (t >= PROWS * 768) return;
    int r = t / 768, j = t % 768;
    int b = r / 196, p = r % 196;
    int ph = p / 14, pw = p % 14;
    int p1 = j / 48, jr = j % 48;
    int p2 = jr / 3, c = jr % 3;
    float v = img[(((size_t)b * 3 + c) * 224 + ph * 16 + p1) * 224 + pw * 16 + p2];
    Xp[t] = __float2bfloat16(v);
}

__global__ void cls_init_kernel(const float* __restrict__ cls, const float* __restrict__ pos,
                                float* __restrict__ xf, hb* __restrict__ xb) {
    int t = blockIdx.x * 256 + threadIdx.x;   // 64*512
    int b = t >> 9, c = t & 511;
    float v = cls[c] + pos[c];
    size_t off = ((size_t)b * N_TOK) * N_DIM + c;
    xf[off] = v;
    xb[off] = __float2bfloat16(v);
}

__global__ void zero_pads_kernel(float* __restrict__ xf, hb* __restrict__ xb, hb* __restrict__ ctx) {
    int t = blockIdx.x * 256 + threadIdx.x;   // 64*512 pad elements
    size_t off = (size_t)ROWS * N_DIM + t;
    xf[off] = 0.f;
    xb[off] = __float2bfloat16(0.f);
    ctx[off] = __float2bfloat16(0.f);
}

__global__ void extract_cls_kernel(const float* __restrict__ xf, float* __restrict__ out) {
    int t = blockIdx.x * 256 + threadIdx.x;   // 64*512
    int b = t >> 9, c = t & 511;
    out[t] = xf[((size_t)b * N_TOK) * N_DIM + c];
}

// ---------------- LayerNorm (fp32 in -> fp32 + bf16 out), 1 wave per row ----------------

__global__ void __launch_bounds__(256) ln_kernel(const float* __restrict__ in,
                                                 const float* __restrict__ w, const float* __restrict__ b,
                                                 float* __restrict__ outf, hb* __restrict__ outb, int rows) {
    int row = blockIdx.x * 4 + (threadIdx.x >> 6);
    int lane = threadIdx.x & 63;
    if (row >= rows) return;
    const float* p = in + (size_t)row * N_DIM;
    float4 v0 = *(const float4*)(p + lane * 8);
    float4 v1 = *(const float4*)(p + lane * 8 + 4);
    float xs[8] = {v0.x, v0.y, v0.z, v0.w, v1.x, v1.y, v1.z, v1.w};
    float s = 0.f, q = 0.f;
#pragma unroll
    for (int j = 0; j < 8; ++j) { s += xs[j]; q += xs[j] * xs[j]; }
#pragma unroll
    for (int o = 32; o > 0; o >>= 1) { s += __shfl_xor(s, o); q += __shfl_xor(q, o); }
    float mean = s * (1.f / 512.f);
    float var = q * (1.f / 512.f) - mean * mean;
    float r = rsqrtf(var + 1e-5f);
    float4 w0 = *(const float4*)(w + lane * 8);
    float4 w1 = *(const float4*)(w + lane * 8 + 4);
    float4 b0 = *(const float4*)(b + lane * 8);
    float4 b1 = *(const float4*)(b + lane * 8 + 4);
    float ws8[8] = {w0.x, w0.y, w0.z, w0.w, w1.x, w1.y, w1.z, w1.w};
    float bs8[8] = {b0.x, b0.y, b0.z, b0.w, b1.x, b1.y, b1.z, b1.w};
    float of[8] __attribute__((aligned(16)));
    hb tb[8] __attribute__((aligned(16)));
#pragma unroll
    for (int j = 0; j < 8; ++j) {
        float y = (xs[j] - mean) * r * ws8[j] + bs8[j];
        of[j] = y;
        tb[j] = __float2bfloat16(y);
    }
    *(float4*)(outf + (size_t)row * N_DIM + lane * 8)     = *(const float4*)&of[0];
    *(float4*)(outf + (size_t)row * N_DIM + lane * 8 + 4) = *(const float4*)&of[4];
    *(float4*)(outb + (size_t)row * N_DIM + lane * 8)     = *(const float4*)&tb[0];
}

// ---------------- GEMM: C[M,N] = A[M,K] @ B[N,K]^T + bias, epilogue variants ----------------
// MODE 0: out_bf = acc + bias                      (qkv)
// MODE 1: out_bf = gelu(acc + bias)                (fc1)
// MODE 2: out_f32 = acc + bias + res_f32           (out_proj, fc2)
// MODE 3: patch embed: row remap + pos_emb, writes both f32 and bf16

template <int MODE>
__global__ void __launch_bounds__(256) gemm_bt(const hb* __restrict__ A, const hb* __restrict__ B,
                                               const float* __restrict__ bias, int K, int N,
                                               hb* __restrict__ outb, float* __restrict__ outf,
                                               const float* __restrict__ res, const float* __restrict__ pos) {
    __shared__ float4 As[512];   // 128 rows x 32 bf16 (4 chunks of 16B per row)
    __shared__ float4 Bs[512];
    const int tid = threadIdx.x;
    const int lane = tid & 63, wid = tid >> 6;
    const int wr = wid >> 1, wc = wid & 1;
    const int quad = lane >> 4, r16 = lane & 15;
    const int m0 = blockIdx.y * 128, n0 = blockIdx.x * 128;

    f32x4 acc[4][4] = {};

    for (int k0 = 0; k0 < K; k0 += 32) {
#pragma unroll
        for (int i = 0; i < 2; ++i) {
            int q = tid + (i << 8);
            int row = q >> 2, kc = q & 3;
            As[q] = *(const float4*)(A + (size_t)(m0 + row) * K + k0 + kc * 8);
            Bs[q] = *(const float4*)(B + (size_t)(n0 + row) * K + k0 + kc * 8);
        }
        __syncthreads();
        bf16x8 af[4], bfr[4];
#pragma unroll
        for (int t = 0; t < 4; ++t) {
            af[t]  = __builtin_bit_cast(bf16x8, As[(wr * 64 + t * 16 + r16) * 4 + quad]);
            bfr[t] = __builtin_bit_cast(bf16x8, Bs[(wc * 64 + t * 16 + r16) * 4 + quad]);
        }
#pragma unroll
        for (int mi = 0; mi < 4; ++mi)
#pragma unroll
            for (int nj = 0; nj < 4; ++nj)
                acc[mi][nj] = __builtin_amdgcn_mfma_f32_16x16x32_bf16(af[mi], bfr[nj], acc[mi][nj], 0, 0, 0);
        __syncthreads();
    }

#pragma unroll
    for (int nj = 0; nj < 4; ++nj) {
        int col = n0 + wc * 64 + nj * 16 + r16;
        float bv = bias[col];
#pragma unroll
        for (int mi = 0; mi < 4; ++mi) {
#pragma unroll
            for (int e = 0; e < 4; ++e) {
                int row = m0 + wr * 64 + mi * 16 + quad * 4 + e;
                float v = acc[mi][nj][e] + bv;
                if constexpr (MODE == 0) {
                    outb[(size_t)row * N + col] = __float2bfloat16(v);
                } else if constexpr (MODE == 1) {
                    v = 0.5f * v * (1.f + erff(v * 0.70710678118654752f));
                    outb[(size_t)row * N + col] = __float2bfloat16(v);
                } else if constexpr (MODE == 2) {
                    v += res[(size_t)row * N + col];
                    outf[(size_t)row * N + col] = v;
                } else {  // MODE 3: patch embed
                    int pidx = row % 196;
                    int row2 = row + row / 196 + 1;
                    v += pos[(size_t)(pidx + 1) * N_DIM + col];
                    outf[(size_t)row2 * N_DIM + col] = v;
                    outb[(size_t)row2 * N_DIM + col] = __float2bfloat16(v);
                }
            }
        }
    }
}

// ---------------- Attention: one block per (b, h); VALU impl ----------------
// qkv row layout: [q(512) | k(512) | v(512)], head h occupies cols h*64..h*64+63.

__global__ void __launch_bounds__(256) attn_kernel(const hb* __restrict__ qkv, hb* __restrict__ ctx) {
    __shared__ float Kt[64][209];     // K^T, padded cols (197 real + zero fill to 208)
    __shared__ float probs[4][200];   // per-wave unnormalized softmax numerators
    const int b = blockIdx.x >> 3, h = blockIdx.x & 7;
    const int tid = threadIdx.x, lane = tid & 63, wid = tid >> 6;
    const hb* base = qkv + (size_t)b * N_TOK * 1536;

    // stage K^T (bf16 -> fp32, exact)
    for (int idx = tid; idx < N_TOK * 64; idx += 256) {
        int m = idx >> 6, d = idx & 63;
        Kt[d][m] = __bfloat162float(base[(size_t)m * 1536 + 512 + h * 64 + d]);
    }
    // zero-fill pad keys 197..208
    for (int idx = tid; idx < 64 * 12; idx += 256) {
        int d = idx / 12, m = 197 + idx % 12;
        Kt[d][m] = 0.f;
    }
    __syncthreads();

    const int m3 = (lane + 192 > 208) ? 208 : (lane + 192);   // clamped: pad entries are 0
    const hb* vbase = base + 1024 + h * 64 + lane;

    for (int n = wid; n < N_TOK; n += 4) {
        float qv = 0.125f * __bfloat162float(base[(size_t)n * 1536 + h * 64 + lane]);
        float s0 = 0.f, s1 = 0.f, s2 = 0.f, s3 = 0.f;
#pragma unroll 4
        for (int d = 0; d < 64; ++d) {
            float qd = __shfl(qv, d);
            s0 += qd * Kt[d][lane];
            s1 += qd * Kt[d][lane + 64];
            s2 += qd * Kt[d][lane + 128];
            s3 += qd * Kt[d][m3];
        }
        if (lane >= 5) s3 = -1e30f;   // keys >= 197 invalid
        float mx = fmaxf(fmaxf(s0, s1), fmaxf(s2, s3));
#pragma unroll
        for (int o = 32; o > 0; o >>= 1) mx = fmaxf(mx, __shfl_xor(mx, o));
        float e0 = __expf(s0 - mx), e1 = __expf(s1 - mx), e2 = __expf(s2 - mx), e3 = __expf(s3 - mx);
        float sm = e0 + e1 + e2 + e3;
#pragma unroll
        for (int o = 32; o > 0; o >>= 1) sm += __shfl_xor(sm, o);
        float rs = 1.f / sm;
        probs[wid][lane] = e0;
        probs[wid][lane + 64] = e1;
        probs[wid][lane + 128] = e2;
        if (lane < 5) probs[wid][lane + 192] = e3;
        asm volatile("s_waitcnt lgkmcnt(0)" ::: "memory");

        // ctx[n][h*64+lane] = sum_m probs[m] * V[m][lane]  (V streamed via L1)
        float acc = 0.f;
        const float4* p4 = (const float4*)&probs[wid][0];
#pragma unroll 2
        for (int mm = 0; mm < 49; ++mm) {
            float4 p = p4[mm];
            int m = mm * 4;
            acc += p.x * __bfloat162float(vbase[(size_t)(m + 0) * 1536]);
            acc += p.y * __bfloat162float(vbase[(size_t)(m + 1) * 1536]);
            acc += p.z * __bfloat162float(vbase[(size_t)(m + 2) * 1536]);
            acc += p.w * __bfloat162float(vbase[(size_t)(m + 3) * 1536]);
        }
        acc += probs[wid][196] * __bfloat162float(vbase[(size_t)196 * 1536]);
        acc *= rs;
        ctx[((size_t)b * N_TOK + n) * N_DIM + h * 64 + lane] = __float2bfloat16(acc);
    }
}

// ---------------- launch ----------------

extern "C" void kernel_launch(void* const* d_in, const int* in_sizes, int n_in,
                              void* d_out, int out_size, void* d_ws, size_t ws_size,
                              hipStream_t stream) {
    (void)in_sizes; (void)n_in; (void)out_size; (void)ws_size;
    const float* img     = (const float*)d_in[0];
    const float* patch_w = (const float*)d_in[1];
    const float* patch_b = (const float*)d_in[2];
    const float* cls_t   = (const float*)d_in[3];
    const float* pos     = (const float*)d_in[4];
    const float* w_qkv   = (const float*)d_in[5];
    const float* b_qkv   = (const float*)d_in[6];
    const float* w_out   = (const float*)d_in[7];
    const float* b_out   = (const float*)d_in[8];
    const float* ln1w    = (const float*)d_in[9];
    const float* ln1b    = (const float*)d_in[10];
    const float* w_fc1   = (const float*)d_in[11];
    const float* b_fc1   = (const float*)d_in[12];
    const float* w_fc2   = (const float*)d_in[13];
    const float* b_fc2   = (const float*)d_in[14];
    const float* ln2w    = (const float*)d_in[15];
    const float* ln2b    = (const float*)d_in[16];

    char* ws = (char*)d_ws;
    hb* wPatch = (hb*)(ws + OFF_WPATCH);
    hb* wQKV   = (hb*)(ws + OFF_WQKV);
    hb* wOut   = (hb*)(ws + OFF_WOUT);
    hb* wFc1   = (hb*)(ws + OFF_WFC1);
    hb* wFc2   = (hb*)(ws + OFF_WFC2);
    hb* x_bf   = (hb*)(ws + OFF_XBF);
    hb* ctx    = (hb*)(ws + OFF_CTX);
    hb* Xp     = (hb*)(ws + OFF_BIG);
    hb* qkv    = (hb*)(ws + OFF_BIG);
    hb* hmid   = (hb*)(ws + OFF_BIG);
    float* x_f = (float*)(ws + OFF_XF);
    float* h1  = (float*)(ws + OFF_H1);

    auto cvt = [&](const float* src, hb* dst, int n) {
        cvt_bf16_kernel<<<dim3((n + 255) / 256), dim3(256), 0, stream>>>(src, dst, n);
    };
    cvt(patch_w, wPatch, 512 * 768);
    cvt(w_qkv, wQKV, N_DEPTH * 1536 * 512);
    cvt(w_out, wOut, N_DEPTH * 512 * 512);
    cvt(w_fc1, wFc1, N_DEPTH * 2048 * 512);
    cvt(w_fc2, wFc2, N_DEPTH * 512 * 2048);

    patchify_kernel<<<dim3((PROWS * 768 + 255) / 256), dim3(256), 0, stream>>>(img, Xp);
    gemm_bt<3><<<dim3(4, 98), dim3(256), 0, stream>>>(Xp, wPatch, patch_b, 768, 512, x_bf, x_f, nullptr, pos);
    cls_init_kernel<<<dim3(128), dim3(256), 0, stream>>>(cls_t, pos, x_f, x_bf);
    zero_pads_kernel<<<dim3(128), dim3(256), 0, stream>>>(x_f, x_bf, ctx);

    for (int i = 0; i < N_DEPTH; ++i) {
        gemm_bt<0><<<dim3(12, 99), dim3(256), 0, stream>>>(x_bf, wQKV + (size_t)i * 1536 * 512,
                                                           b_qkv + i * 1536, 512, 1536, qkv, nullptr, nullptr, nullptr);
        attn_kernel<<<dim3(512), dim3(256), 0, stream>>>(qkv, ctx);
        gemm_bt<2><<<dim3(4, 99), dim3(256), 0, stream>>>(ctx, wOut + (size_t)i * 512 * 512,
                                                          b_out + i * 512, 512, 512, nullptr, h1, x_f, nullptr);
        ln_kernel<<<dim3(3152), dim3(256), 0, stream>>>(h1, ln1w + i * 512, ln1b + i * 512, x_f, x_bf, ROWS);
        gemm_bt<1><<<dim3(16, 99), dim3(256), 0, stream>>>(x_bf, wFc1 + (size_t)i * 2048 * 512,
                                                           b_fc1 + i * 2048, 512, 2048, hmid, nullptr, nullptr, nullptr);
        gemm_bt<2><<<dim3(4, 99), dim3(256), 0, stream>>>(hmid, wFc2 + (size_t)i * 512 * 2048,
                                                          b_fc2 + i * 512, 2048, 512, nullptr, h1, x_f, nullptr);
        ln_kernel<<<dim3(3152), dim3(256), 0, stream>>>(h1, ln2w + i * 512, ln2b + i * 512, x_f, x_bf, ROWS);
    }

    extract_cls_kernel<<<dim3(128), dim3(256), 0, stream>>>(x_f, (float*)d_out);
}

// Round 2
// 1781.932 us; speedup vs baseline: 2.6647x; 2.6647x over previous
//
#include <hip/hip_runtime.h>
#include <hip/hip_bf16.h>

typedef __hip_bfloat16 hb;
typedef __bf16 bf16x8 __attribute__((ext_vector_type(8)));
typedef float f32x4 __attribute__((ext_vector_type(4)));

#define N_DEPTH 6
#define N_DIM   512
#define N_HEADS 8
#define N_MLP   2048
#define N_TOK   197
#define N_PATCH 196
#define N_BATCH 64
#define ROWS    (N_BATCH * N_TOK)     /* 12608 */
#define ROWS_PAD 12672                /* 99 * 128 */
#define PROWS   (N_BATCH * N_PATCH)   /* 12544 = 98 * 128 */

// ---------------- workspace layout (bytes) ----------------
#define OFF_WPATCH 0u
#define OFF_WQKV   786432u
#define OFF_WOUT   10223616u
#define OFF_WFC1   13369344u
#define OFF_WFC2   25952256u
#define OFF_XBF    38535168u
#define OFF_CTX    51511296u
#define OFF_BIG    64487424u      /* shared slot: Xp / qkv / h_mlp (51,904,512 B) */
#define OFF_XF     116391936u
#define OFF_H1     142344192u     /* fp32 h1 (25.95 MB); vtg (14.68 MB) aliases this:
                                     lifetime: qkv-gemm writes vtg -> attn reads vtg ->
                                     out-proj overwrites h1. Disjoint in time. */
/* total 168,296,448 B */

// ---------------- small utility kernels ----------------

__global__ void cvt_bf16_kernel(const float* __restrict__ in, hb* __restrict__ out, int n) {
    int t = blockIdx.x * 256 + threadIdx.x;
    if (t < n) out[t] = __float2bfloat16(in[t]);
}

// Xp[r][j]: r = b*196 + ph*14 + pw ; j = p1*48 + p2*3 + c ; pixel img[b,c,ph*16+p1,pw*16+p2]
__global__ void patchify_kernel(const float* __restrict__ img, hb* __restrict__ Xp) {
    int t = blockIdx.x * 256 + threadIdx.x;
    if (t >= PROWS * 768) return;
    int r = t / 768, j = t % 768;
    int b = r / 196, p = r % 196;
    int ph = p / 14, pw = p % 14;
    int p1 = j / 48, jr = j % 48;
    int p2 = jr / 3, c = jr % 3;
    float v = img[(((size_t)b * 3 + c) * 224 + ph * 16 + p1) * 224 + pw * 16 + p2];
    Xp[t] = __float2bfloat16(v);
}

__global__ void cls_init_kernel(const float* __restrict__ cls, const float* __restrict__ pos,
                                float* __restrict__ xf, hb* __restrict__ xb) {
    int t = blockIdx.x * 256 + threadIdx.x;   // 64*512
    int b = t >> 9, c = t & 511;
    float v = cls[c] + pos[c];
    size_t off = ((size_t)b * N_TOK) * N_DIM + c;
    xf[off] = v;
    xb[off] = __float2bfloat16(v);
}

__global__ void zero_pads_kernel(float* __restrict__ xf, hb* __restrict__ xb, hb* __restrict__ ctx) {
    int t = blockIdx.x * 256 + threadIdx.x;   // 64*512 pad elements
    size_t off = (size_t)ROWS * N_DIM + t;
    xf[off] = 0.f;
    xb[off] = __float2bfloat16(0.f);
    ctx[off] = __float2bfloat16(0.f);
}

__global__ void extract_cls_kernel(const float* __restrict__ xf, float* __restrict__ out) {
    int t = blockIdx.x * 256 + threadIdx.x;   // 64*512
    int b = t >> 9, c = t & 511;
    out[t] = xf[((size_t)b * N_TOK) * N_DIM + c];
}

// ---------------- LayerNorm (fp32 in -> fp32 + bf16 out), 1 wave per row ----------------

__global__ void __launch_bounds__(256) ln_kernel(const float* __restrict__ in,
                                                 const float* __restrict__ w, const float* __restrict__ b,
                                                 float* __restrict__ outf, hb* __restrict__ outb, int rows) {
    int row = blockIdx.x * 4 + (threadIdx.x >> 6);
    int lane = threadIdx.x & 63;
    if (row >= rows) return;
    const float* p = in + (size_t)row * N_DIM;
    float4 v0 = *(const float4*)(p + lane * 8);
    float4 v1 = *(const float4*)(p + lane * 8 + 4);
    float xs[8] = {v0.x, v0.y, v0.z, v0.w, v1.x, v1.y, v1.z, v1.w};
    float s = 0.f, q = 0.f;
#pragma unroll
    for (int j = 0; j < 8; ++j) { s += xs[j]; q += xs[j] * xs[j]; }
#pragma unroll
    for (int o = 32; o > 0; o >>= 1) { s += __shfl_xor(s, o); q += __shfl_xor(q, o); }
    float mean = s * (1.f / 512.f);
    float var = q * (1.f / 512.f) - mean * mean;
    float r = rsqrtf(var + 1e-5f);
    float4 w0 = *(const float4*)(w + lane * 8);
    float4 w1 = *(const float4*)(w + lane * 8 + 4);
    float4 b0 = *(const float4*)(b + lane * 8);
    float4 b1 = *(const float4*)(b + lane * 8 + 4);
    float ws8[8] = {w0.x, w0.y, w0.z, w0.w, w1.x, w1.y, w1.z, w1.w};
    float bs8[8] = {b0.x, b0.y, b0.z, b0.w, b1.x, b1.y, b1.z, b1.w};
    float of[8] __attribute__((aligned(16)));
    hb tb[8] __attribute__((aligned(16)));
#pragma unroll
    for (int j = 0; j < 8; ++j) {
        float y = (xs[j] - mean) * r * ws8[j] + bs8[j];
        of[j] = y;
        tb[j] = __float2bfloat16(y);
    }
    *(float4*)(outf + (size_t)row * N_DIM + lane * 8)     = *(const float4*)&of[0];
    *(float4*)(outf + (size_t)row * N_DIM + lane * 8 + 4) = *(const float4*)&of[4];
    *(float4*)(outb + (size_t)row * N_DIM + lane * 8)     = *(const float4*)&tb[0];
}

// ---------------- GEMM: C[M,N] = A[M,K] @ B[N,K]^T + bias, epilogue variants ----------------
// MODE 0: out_bf = acc + bias; V-columns also scatter to vtg transposed   (qkv)
// MODE 1: out_bf = gelu(acc + bias)                (fc1)
// MODE 2: out_f32 = acc + bias + res_f32           (out_proj, fc2)
// MODE 3: patch embed: row remap + pos_emb, writes both f32 and bf16

template <int MODE>
__global__ void __launch_bounds__(256) gemm_bt(const hb* __restrict__ A, const hb* __restrict__ B,
                                               const float* __restrict__ bias, int K, int N,
                                               hb* __restrict__ outb, float* __restrict__ outf,
                                               const float* __restrict__ res, const float* __restrict__ pos,
                                               hb* __restrict__ vtg) {
    __shared__ float4 As[512];   // 128 rows x 32 bf16 (4 chunks of 16B per row)
    __shared__ float4 Bs[512];
    const int tid = threadIdx.x;
    const int lane = tid & 63, wid = tid >> 6;
    const int wr = wid >> 1, wc = wid & 1;
    const int quad = lane >> 4, r16 = lane & 15;
    const int m0 = blockIdx.y * 128, n0 = blockIdx.x * 128;

    f32x4 acc[4][4] = {};

    for (int k0 = 0; k0 < K; k0 += 32) {
#pragma unroll
        for (int i = 0; i < 2; ++i) {
            int q = tid + (i << 8);
            int row = q >> 2, kc = q & 3;
            As[q] = *(const float4*)(A + (size_t)(m0 + row) * K + k0 + kc * 8);
            Bs[q] = *(const float4*)(B + (size_t)(n0 + row) * K + k0 + kc * 8);
        }
        __syncthreads();
        bf16x8 af[4], bfr[4];
#pragma unroll
        for (int t = 0; t < 4; ++t) {
            af[t]  = __builtin_bit_cast(bf16x8, As[(wr * 64 + t * 16 + r16) * 4 + quad]);
            bfr[t] = __builtin_bit_cast(bf16x8, Bs[(wc * 64 + t * 16 + r16) * 4 + quad]);
        }
#pragma unroll
        for (int mi = 0; mi < 4; ++mi)
#pragma unroll
            for (int nj = 0; nj < 4; ++nj)
                acc[mi][nj] = __builtin_amdgcn_mfma_f32_16x16x32_bf16(af[mi], bfr[nj], acc[mi][nj], 0, 0, 0);
        __syncthreads();
    }

    if constexpr (MODE == 0) {
        const bool isv = (n0 >= 1024);   // uniform: this block covers V columns
#pragma unroll
        for (int mi = 0; mi < 4; ++mi) {
#pragma unroll
            for (int e = 0; e < 4; ++e) {
                int row = m0 + wr * 64 + mi * 16 + quad * 4 + e;
                int bb = row / 197;
                int mm = row - bb * 197;
#pragma unroll
                for (int nj = 0; nj < 4; ++nj) {
                    int col = n0 + wc * 64 + nj * 16 + r16;
                    float v = acc[mi][nj][e] + bias[col];
                    hb hv = __float2bfloat16(v);
                    outb[(size_t)row * N + col] = hv;
                    if (isv && bb < 64) {
                        int d = col - 1024;
                        vtg[((size_t)(bb * 8 + (d >> 6))) * (64 * 224) + (size_t)(d & 63) * 224 + mm] = hv;
                    }
                }
            }
        }
    } else {
#pragma unroll
        for (int nj = 0; nj < 4; ++nj) {
            int col = n0 + wc * 64 + nj * 16 + r16;
            float bv = bias[col];
#pragma unroll
            for (int mi = 0; mi < 4; ++mi) {
#pragma unroll
                for (int e = 0; e < 4; ++e) {
                    int row = m0 + wr * 64 + mi * 16 + quad * 4 + e;
                    float v = acc[mi][nj][e] + bv;
                    if constexpr (MODE == 1) {
                        v = 0.5f * v * (1.f + erff(v * 0.70710678118654752f));
                        outb[(size_t)row * N + col] = __float2bfloat16(v);
                    } else if constexpr (MODE == 2) {
                        v += res[(size_t)row * N + col];
                        outf[(size_t)row * N + col] = v;
                    } else {  // MODE 3: patch embed
                        int pidx = row % 196;
                        int row2 = row + row / 196 + 1;
                        v += pos[(size_t)(pidx + 1) * N_DIM + col];
                        outf[(size_t)row2 * N_DIM + col] = v;
                        outb[(size_t)row2 * N_DIM + col] = __float2bfloat16(v);
                    }
                }
            }
        }
    }
}

// ---------------- MFMA flash attention: one block per (b, h) ----------------
// qkv row: [q(512)|k(512)|v(512)], head h at cols h*64..h*64+63.
// vtg[(b*8+h)][d][m] = V^T, written by the qkv GEMM epilogue (m<197 only; tail
// zero-guarded during staging here).

__global__ void __launch_bounds__(256, 2) attn_kernel(const hb* __restrict__ qkv,
                                                      const hb* __restrict__ vtg,
                                                      hb* __restrict__ ctx) {
    __shared__ hb Ks[224 * 64];      // K  [key][d]     28,672 B
    __shared__ hb Vt[64 * 224];      // V^T[d][key]     28,672 B
    __shared__ hb Pb[4][16 * 40];    // per-wave P bounce, stride 40 (16B-aligned rows)
    const int bh = blockIdx.x;
    const int b = bh >> 3, h = bh & 7;
    const int tid = threadIdx.x, lane = tid & 63, wid = tid >> 6;
    const int quad = lane >> 4, r16 = lane & 15;
    const hb* base = qkv + (size_t)(b * N_TOK) * 1536 + h * 64;
    const hb* vbase = vtg + (size_t)bh * (64 * 224);

    // stage K: rows m<197 from global, m>=197 zero
#pragma unroll
    for (int i = 0; i < 7; ++i) {
        int idx = tid + i * 256;               // 1792 16B chunks
        int m = idx >> 3, c = idx & 7;
        bf16x8 val = {};
        if (m < 197) val = *(const bf16x8*)(base + (size_t)m * 1536 + 512 + c * 8);
        *(bf16x8*)&Ks[m * 64 + c * 8] = val;
    }
    // stage V^T: m<192 vectorized from vtg; tail scalar with zero-pad
#pragma unroll
    for (int i = 0; i < 6; ++i) {
        int idx = tid + i * 256;               // 1536 16B chunks (64 d x 24 chunks)
        int d = idx / 24, mc = idx % 24;
        *(bf16x8*)&Vt[d * 224 + mc * 8] = *(const bf16x8*)(vbase + d * 224 + mc * 8);
    }
    const hb hzero = __float2bfloat16(0.f);
#pragma unroll
    for (int i = 0; i < 8; ++i) {
        int idx = tid + i * 256;               // 2048 scalars (64 d x 32 m)
        int d = idx >> 5, m = 192 + (idx & 31);
        Vt[d * 224 + m] = (m < 197) ? vbase[d * 224 + m] : hzero;
    }

    // Q fragments: 64 query rows per wave (rows wid*64 .. wid*64+63; pad rows >=197 garbage, unused)
    bf16x8 af[4][2];
#pragma unroll
    for (int mi = 0; mi < 4; ++mi) {
        int q = wid * 64 + mi * 16 + r16;
#pragma unroll
        for (int kc = 0; kc < 2; ++kc)
            af[mi][kc] = *(const bf16x8*)(base + (size_t)q * 1536 + kc * 32 + quad * 8);
    }

    f32x4 o[4][4] = {};
    float mst[4][4], lp[4][4];
#pragma unroll
    for (int mi = 0; mi < 4; ++mi)
#pragma unroll
        for (int e = 0; e < 4; ++e) { mst[mi][e] = -3.0e38f; lp[mi][e] = 0.f; }

    __syncthreads();

    for (int kt = 0; kt < 7; ++kt) {
        bf16x8 bk[2][2], bv[4];
#pragma unroll
        for (int nj = 0; nj < 2; ++nj)
#pragma unroll
            for (int kc = 0; kc < 2; ++kc)
                bk[nj][kc] = *(const bf16x8*)&Ks[(kt * 32 + nj * 16 + r16) * 64 + kc * 32 + quad * 8];
#pragma unroll
        for (int jd = 0; jd < 4; ++jd)
            bv[jd] = *(const bf16x8*)&Vt[(jd * 16 + r16) * 224 + kt * 32 + quad * 8];

        const bool v0 = (kt * 32 + r16) < N_TOK;
        const bool v1 = (kt * 32 + 16 + r16) < N_TOK;

#pragma unroll
        for (int mi = 0; mi < 4; ++mi) {
            f32x4 z = {};
            f32x4 s0v = __builtin_amdgcn_mfma_f32_16x16x32_bf16(af[mi][0], bk[0][0], z, 0, 0, 0);
            s0v = __builtin_amdgcn_mfma_f32_16x16x32_bf16(af[mi][1], bk[0][1], s0v, 0, 0, 0);
            f32x4 s1v = __builtin_amdgcn_mfma_f32_16x16x32_bf16(af[mi][0], bk[1][0], z, 0, 0, 0);
            s1v = __builtin_amdgcn_mfma_f32_16x16x32_bf16(af[mi][1], bk[1][1], s1v, 0, 0, 0);

            float al[4];
#pragma unroll
            for (int e = 0; e < 4; ++e) {
                float s0 = v0 ? s0v[e] * 0.125f : -1e30f;
                float s1 = v1 ? s1v[e] * 0.125f : -1e30f;
                float mx = fmaxf(s0, s1);
#pragma unroll
                for (int off = 1; off < 16; off <<= 1) mx = fmaxf(mx, __shfl_xor(mx, off));
                float mnew = fmaxf(mst[mi][e], mx);
                float alpha = __expf(mst[mi][e] - mnew);
                mst[mi][e] = mnew;
                float p0 = __expf(s0 - mnew);
                float p1 = __expf(s1 - mnew);
                // lane-partial l accumulation: reduced across the 16-lane group once, at the end
                lp[mi][e] = lp[mi][e] * alpha + p0 + p1;
                al[e] = alpha;
                int prow = (quad * 4 + e) * 40;
                Pb[wid][prow + r16]      = __float2bfloat16(p0);
                Pb[wid][prow + 16 + r16] = __float2bfloat16(p1);
            }
#pragma unroll
            for (int jd = 0; jd < 4; ++jd)
#pragma unroll
                for (int e = 0; e < 4; ++e) o[mi][jd][e] *= al[e];
            // C-layout -> A-layout transform via per-wave LDS bounce (wave-private: no barrier)
            bf16x8 ap = *(const bf16x8*)&Pb[wid][r16 * 40 + quad * 8];
#pragma unroll
            for (int jd = 0; jd < 4; ++jd)
                o[mi][jd] = __builtin_amdgcn_mfma_f32_16x16x32_bf16(ap, bv[jd], o[mi][jd], 0, 0, 0);
        }
    }

    // epilogue: final l reduction + normalized store
#pragma unroll
    for (int mi = 0; mi < 4; ++mi) {
        float rl[4];
#pragma unroll
        for (int e = 0; e < 4; ++e) {
            float l = lp[mi][e];
#pragma unroll
            for (int off = 1; off < 16; off <<= 1) l += __shfl_xor(l, off);
            rl[e] = 1.f / l;
        }
        int qrow = wid * 64 + mi * 16 + quad * 4;
#pragma unroll
        for (int e = 0; e < 4; ++e) {
            int q = qrow + e;
            if (q < N_TOK) {
                hb* dst = ctx + ((size_t)(b * N_TOK + q)) * N_DIM + h * 64;
#pragma unroll
                for (int jd = 0; jd < 4; ++jd)
                    dst[jd * 16 + r16] = __float2bfloat16(o[mi][jd][e] * rl[e]);
            }
        }
    }
}

// ---------------- launch ----------------

extern "C" void kernel_launch(void* const* d_in, const int* in_sizes, int n_in,
                              void* d_out, int out_size, void* d_ws, size_t ws_size,
                              hipStream_t stream) {
    (void)in_sizes; (void)n_in; (void)out_size; (void)ws_size;
    const float* img     = (const float*)d_in[0];
    const float* patch_w = (const float*)d_in[1];
    const float* patch_b = (const float*)d_in[2];
    const float* cls_t   = (const float*)d_in[3];
    const float* pos     = (const float*)d_in[4];
    const float* w_qkv   = (const float*)d_in[5];
    const float* b_qkv   = (const float*)d_in[6];
    const float* w_out   = (const float*)d_in[7];
    const float* b_out   = (const float*)d_in[8];
    const float* ln1w    = (const float*)d_in[9];
    const float* ln1b    = (const float*)d_in[10];
    const float* w_fc1   = (const float*)d_in[11];
    const float* b_fc1   = (const float*)d_in[12];
    const float* w_fc2   = (const float*)d_in[13];
    const float* b_fc2   = (const float*)d_in[14];
    const float* ln2w    = (const float*)d_in[15];
    const float* ln2b    = (const float*)d_in[16];

    char* ws = (char*)d_ws;
    hb* wPatch = (hb*)(ws + OFF_WPATCH);
    hb* wQKV   = (hb*)(ws + OFF_WQKV);
    hb* wOut   = (hb*)(ws + OFF_WOUT);
    hb* wFc1   = (hb*)(ws + OFF_WFC1);
    hb* wFc2   = (hb*)(ws + OFF_WFC2);
    hb* x_bf   = (hb*)(ws + OFF_XBF);
    hb* ctx    = (hb*)(ws + OFF_CTX);
    hb* Xp     = (hb*)(ws + OFF_BIG);
    hb* qkv    = (hb*)(ws + OFF_BIG);
    hb* hmid   = (hb*)(ws + OFF_BIG);
    float* x_f = (float*)(ws + OFF_XF);
    float* h1  = (float*)(ws + OFF_H1);
    hb* vtg    = (hb*)(ws + OFF_H1);   // aliases h1; lifetimes disjoint within a layer

    auto cvt = [&](const float* src, hb* dst, int n) {
        cvt_bf16_kernel<<<dim3((n + 255) / 256), dim3(256), 0, stream>>>(src, dst, n);
    };
    cvt(patch_w, wPatch, 512 * 768);
    cvt(w_qkv, wQKV, N_DEPTH * 1536 * 512);
    cvt(w_out, wOut, N_DEPTH * 512 * 512);
    cvt(w_fc1, wFc1, N_DEPTH * 2048 * 512);
    cvt(w_fc2, wFc2, N_DEPTH * 512 * 2048);

    patchify_kernel<<<dim3((PROWS * 768 + 255) / 256), dim3(256), 0, stream>>>(img, Xp);
    gemm_bt<3><<<dim3(4, 98), dim3(256), 0, stream>>>(Xp, wPatch, patch_b, 768, 512, x_bf, x_f, nullptr, pos, nullptr);
    cls_init_kernel<<<dim3(128), dim3(256), 0, stream>>>(cls_t, pos, x_f, x_bf);
    zero_pads_kernel<<<dim3(128), dim3(256), 0, stream>>>(x_f, x_bf, ctx);

    for (int i = 0; i < N_DEPTH; ++i) {
        gemm_bt<0><<<dim3(12, 99), dim3(256), 0, stream>>>(x_bf, wQKV + (size_t)i * 1536 * 512,
                                                           b_qkv + i * 1536, 512, 1536, qkv, nullptr, nullptr, nullptr, vtg);
        attn_kernel<<<dim3(512), dim3(256), 0, stream>>>(qkv, vtg, ctx);
        gemm_bt<2><<<dim3(4, 99), dim3(256), 0, stream>>>(ctx, wOut + (size_t)i * 512 * 512,
                                                          b_out + i * 512, 512, 512, nullptr, h1, x_f, nullptr, nullptr);
        ln_kernel<<<dim3(3152), dim3(256), 0, stream>>>(h1, ln1w + i * 512, ln1b + i * 512, x_f, x_bf, ROWS);
        gemm_bt<1><<<dim3(16, 99), dim3(256), 0, stream>>>(x_bf, wFc1 + (size_t)i * 2048 * 512,
                                                           b_fc1 + i * 2048, 512, 2048, hmid, nullptr, nullptr, nullptr, nullptr);
        gemm_bt<2><<<dim3(4, 99), dim3(256), 0, stream>>>(hmid, wFc2 + (size_t)i * 512 * 2048,
                                                          b_fc2 + i * 512, 2048, 512, nullptr, h1, x_f, nullptr, nullptr);
        ln_kernel<<<dim3(3152), dim3(256), 0, stream>>>(h1, ln2w + i * 512, ln2b + i * 512, x_f, x_bf, ROWS);
    }

    extract_cls_kernel<<<dim3(128), dim3(256), 0, stream>>>(x_f, (float*)d_out);
}

// Round 3
// 1746.385 us; speedup vs baseline: 2.7189x; 1.0204x over previous
//
#include <hip/hip_runtime.h>
#include <hip/hip_bf16.h>

typedef __hip_bfloat16 hb;
typedef __bf16 bf16x8 __attribute__((ext_vector_type(8)));
typedef float f32x4 __attribute__((ext_vector_type(4)));

#define N_DEPTH 6
#define N_DIM   512
#define N_HEADS 8
#define N_MLP   2048
#define N_TOK   197
#define N_PATCH 196
#define N_BATCH 64
#define ROWS    (N_BATCH * N_TOK)     /* 12608 */
#define ROWS_PAD 12672                /* 99 * 128 */
#define PROWS   (N_BATCH * N_PATCH)   /* 12544 = 98 * 128 */

// ---------------- workspace layout (bytes) ----------------
#define OFF_WPATCH 0u
#define OFF_WQKV   786432u
#define OFF_WOUT   10223616u
#define OFF_WFC1   13369344u
#define OFF_WFC2   25952256u
#define OFF_XBF    38535168u
#define OFF_CTX    51511296u
#define OFF_BIG    64487424u      /* shared slot: Xp / qkv / h_mlp (51,904,512 B) */
#define OFF_XF     116391936u
#define OFF_H1     142344192u     /* fp32 h1 (25.95 MB); vtg (14.68 MB) aliases this:
                                     lifetime: qkv-gemm writes vtg -> attn reads vtg ->
                                     out-proj overwrites h1. Disjoint in time. */
/* total 168,296,448 B */

// async global->LDS, 16B per lane; LDS dest = wave-uniform base + lane*16
__device__ __forceinline__ void gl2lds(const hb* g, hb* l) {
    __builtin_amdgcn_global_load_lds((const __attribute__((address_space(1))) unsigned int*)g,
                                     (__attribute__((address_space(3))) unsigned int*)l, 16, 0, 0);
}

// ---------------- small utility kernels ----------------

__global__ void cvt_bf16_kernel(const float* __restrict__ in, hb* __restrict__ out, int n) {
    int t = blockIdx.x * 256 + threadIdx.x;
    if (t < n) out[t] = __float2bfloat16(in[t]);
}

// Xp[r][j]: r = b*196 + ph*14 + pw ; j = p1*48 + p2*3 + c ; pixel img[b,c,ph*16+p1,pw*16+p2]
__global__ void patchify_kernel(const float* __restrict__ img, hb* __restrict__ Xp) {
    int t = blockIdx.x * 256 + threadIdx.x;
    if (t >= PROWS * 768) return;
    int r = t / 768, j = t % 768;
    int b = r / 196, p = r % 196;
    int ph = p / 14, pw = p % 14;
    int p1 = j / 48, jr = j % 48;
    int p2 = jr / 3, c = jr % 3;
    float v = img[(((size_t)b * 3 + c) * 224 + ph * 16 + p1) * 224 + pw * 16 + p2];
    Xp[t] = __float2bfloat16(v);
}

__global__ void cls_init_kernel(const float* __restrict__ cls, const float* __restrict__ pos,
                                float* __restrict__ xf, hb* __restrict__ xb) {
    int t = blockIdx.x * 256 + threadIdx.x;   // 64*512
    int b = t >> 9, c = t & 511;
    float v = cls[c] + pos[c];
    size_t off = ((size_t)b * N_TOK) * N_DIM + c;
    xf[off] = v;
    xb[off] = __float2bfloat16(v);
}

__global__ void zero_pads_kernel(float* __restrict__ xf, hb* __restrict__ xb, hb* __restrict__ ctx) {
    int t = blockIdx.x * 256 + threadIdx.x;   // 64*512 pad elements
    size_t off = (size_t)ROWS * N_DIM + t;
    xf[off] = 0.f;
    xb[off] = __float2bfloat16(0.f);
    ctx[off] = __float2bfloat16(0.f);
}

__global__ void extract_cls_kernel(const float* __restrict__ xf, float* __restrict__ out) {
    int t = blockIdx.x * 256 + threadIdx.x;   // 64*512
    int b = t >> 9, c = t & 511;
    out[t] = xf[((size_t)b * N_TOK) * N_DIM + c];
}

// ---------------- LayerNorm (fp32 in -> fp32 + bf16 out), 1 wave per row ----------------

__global__ void __launch_bounds__(256) ln_kernel(const float* __restrict__ in,
                                                 const float* __restrict__ w, const float* __restrict__ b,
                                                 float* __restrict__ outf, hb* __restrict__ outb, int rows) {
    int row = blockIdx.x * 4 + (threadIdx.x >> 6);
    int lane = threadIdx.x & 63;
    if (row >= rows) return;
    const float* p = in + (size_t)row * N_DIM;
    float4 v0 = *(const float4*)(p + lane * 8);
    float4 v1 = *(const float4*)(p + lane * 8 + 4);
    float xs[8] = {v0.x, v0.y, v0.z, v0.w, v1.x, v1.y, v1.z, v1.w};
    float s = 0.f, q = 0.f;
#pragma unroll
    for (int j = 0; j < 8; ++j) { s += xs[j]; q += xs[j] * xs[j]; }
#pragma unroll
    for (int o = 32; o > 0; o >>= 1) { s += __shfl_xor(s, o); q += __shfl_xor(q, o); }
    float mean = s * (1.f / 512.f);
    float var = q * (1.f / 512.f) - mean * mean;
    float r = rsqrtf(var + 1e-5f);
    float4 w0 = *(const float4*)(w + lane * 8);
    float4 w1 = *(const float4*)(w + lane * 8 + 4);
    float4 b0 = *(const float4*)(b + lane * 8);
    float4 b1 = *(const float4*)(b + lane * 8 + 4);
    float ws8[8] = {w0.x, w0.y, w0.z, w0.w, w1.x, w1.y, w1.z, w1.w};
    float bs8[8] = {b0.x, b0.y, b0.z, b0.w, b1.x, b1.y, b1.z, b1.w};
    float of[8] __attribute__((aligned(16)));
    hb tb[8] __attribute__((aligned(16)));
#pragma unroll
    for (int j = 0; j < 8; ++j) {
        float y = (xs[j] - mean) * r * ws8[j] + bs8[j];
        of[j] = y;
        tb[j] = __float2bfloat16(y);
    }
    *(float4*)(outf + (size_t)row * N_DIM + lane * 8)     = *(const float4*)&of[0];
    *(float4*)(outf + (size_t)row * N_DIM + lane * 8 + 4) = *(const float4*)&of[4];
    *(float4*)(outb + (size_t)row * N_DIM + lane * 8)     = *(const float4*)&tb[0];
}

// ---------------- GEMM: C[M,N] = A[M,K] @ B[N,K]^T + bias, epilogue variants ----------------
// K-loop: m97 structure — global_load_lds width=16 staging, BK=32, 2 barriers.
// MODE 0: out_bf = acc + bias; V-col blocks also scatter to vtg transposed  (qkv)
// MODE 1: out_bf = gelu(acc + bias)                (fc1)
// MODE 2: out_f32 = acc + bias + res_f32           (out_proj, fc2)
// MODE 3: patch embed: row remap + pos_emb, writes both f32 and bf16

template <int MODE>
__global__ void __launch_bounds__(256) gemm_bt(const hb* __restrict__ A, const hb* __restrict__ B,
                                               const float* __restrict__ bias, int K, int N,
                                               hb* __restrict__ outb, float* __restrict__ outf,
                                               const float* __restrict__ res, const float* __restrict__ pos,
                                               hb* __restrict__ vtg) {
    __shared__ hb Sm[8192];          // As[128][32] | Bs[128][32]; reused as C-bounce in epilogue
    hb* As = Sm;
    hb* Bs = Sm + 4096;
    const int tid = threadIdx.x;
    const int lane = tid & 63, wid = tid >> 6;
    const int wr = wid >> 1, wc = wid & 1;
    const int quad = lane >> 4, r16 = lane & 15;
    const int m0 = blockIdx.y * 128, n0 = blockIdx.x * 128;

    // staging addresses: wave w stages rows [32w, 32w+32) of each tile.
    // lane i covers row 32w + (i>>2), 16B chunk (i&3); LDS dest = base + lane*16.
    const int r0 = lane >> 2, c0 = lane & 3;
    const hb* ga0 = A + (size_t)(m0 + wid * 32 + r0) * K + c0 * 8;
    const hb* ga1 = ga0 + (size_t)16 * K;
    const hb* gb0 = B + (size_t)(n0 + wid * 32 + r0) * K + c0 * 8;
    const hb* gb1 = gb0 + (size_t)16 * K;
    hb* la0 = As + (wid * 32) * 32;       // wave-uniform LDS bases
    hb* la1 = As + (wid * 32 + 16) * 32;
    hb* lb0 = Bs + (wid * 32) * 32;
    hb* lb1 = Bs + (wid * 32 + 16) * 32;

    f32x4 acc[4][4] = {};

    for (int k0 = 0; k0 < K; k0 += 32) {
        gl2lds(ga0, la0);
        gl2lds(ga1, la1);
        gl2lds(gb0, lb0);
        gl2lds(gb1, lb1);
        ga0 += 32; ga1 += 32; gb0 += 32; gb1 += 32;
        __syncthreads();
        bf16x8 af[4], bfr[4];
#pragma unroll
        for (int t = 0; t < 4; ++t) {
            af[t]  = *(const bf16x8*)&As[(wr * 64 + t * 16 + r16) * 32 + quad * 8];
            bfr[t] = *(const bf16x8*)&Bs[(wc * 64 + t * 16 + r16) * 32 + quad * 8];
        }
#pragma unroll
        for (int mi = 0; mi < 4; ++mi)
#pragma unroll
            for (int nj = 0; nj < 4; ++nj)
                acc[mi][nj] = __builtin_amdgcn_mfma_f32_16x16x32_bf16(af[mi], bfr[nj], acc[mi][nj], 0, 0, 0);
        __syncthreads();
    }

    if constexpr (MODE == 0 || MODE == 1) {
        const bool isv = (MODE == 0) && (n0 >= 1024);   // uniform per block
        if (!isv) {
            // coalesced epilogue: per-wave 64x32 LDS bounce (wave-private, in-order LDS)
            hb* Cb = Sm + wid * 2048;
#pragma unroll
            for (int p = 0; p < 2; ++p) {
#pragma unroll
                for (int nj2 = 0; nj2 < 2; ++nj2) {
                    int nj = p * 2 + nj2;
                    float bv = bias[n0 + wc * 64 + nj * 16 + r16];
#pragma unroll
                    for (int mi = 0; mi < 4; ++mi)
#pragma unroll
                        for (int e = 0; e < 4; ++e) {
                            float v = acc[mi][nj][e] + bv;
                            if constexpr (MODE == 1)
                                v = 0.5f * v * (1.f + erff(v * 0.70710678118654752f));
                            Cb[(mi * 16 + quad * 4 + e) * 32 + nj2 * 16 + r16] = __float2bfloat16(v);
                        }
                }
#pragma unroll
                for (int it = 0; it < 4; ++it) {
                    int idx = it * 64 + lane;
                    int row = idx >> 2, ch = idx & 3;
                    bf16x8 val = *(const bf16x8*)&Cb[row * 32 + ch * 8];
                    *(bf16x8*)(outb + (size_t)(m0 + wr * 64 + row) * N + n0 + wc * 64 + p * 32 + ch * 8) = val;
                }
            }
        } else {
            // V columns: scalar store + transposed scatter into vtg
#pragma unroll
            for (int mi = 0; mi < 4; ++mi) {
#pragma unroll
                for (int e = 0; e < 4; ++e) {
                    int row = m0 + wr * 64 + mi * 16 + quad * 4 + e;
                    int bb = row / 197;
                    int mm = row - bb * 197;
#pragma unroll
                    for (int nj = 0; nj < 4; ++nj) {
                        int col = n0 + wc * 64 + nj * 16 + r16;
                        float v = acc[mi][nj][e] + bias[col];
                        hb hv = __float2bfloat16(v);
                        outb[(size_t)row * N + col] = hv;
                        if (bb < 64) {
                            int d = col - 1024;
                            vtg[((size_t)(bb * 8 + (d >> 6))) * (64 * 224) + (size_t)(d & 63) * 224 + mm] = hv;
                        }
                    }
                }
            }
        }
    } else {
#pragma unroll
        for (int nj = 0; nj < 4; ++nj) {
            int col = n0 + wc * 64 + nj * 16 + r16;
            float bv = bias[col];
#pragma unroll
            for (int mi = 0; mi < 4; ++mi) {
#pragma unroll
                for (int e = 0; e < 4; ++e) {
                    int row = m0 + wr * 64 + mi * 16 + quad * 4 + e;
                    float v = acc[mi][nj][e] + bv;
                    if constexpr (MODE == 2) {
                        v += res[(size_t)row * N + col];
                        outf[(size_t)row * N + col] = v;
                    } else {  // MODE 3: patch embed
                        int pidx = row % 196;
                        int row2 = row + row / 196 + 1;
                        v += pos[(size_t)(pidx + 1) * N_DIM + col];
                        outf[(size_t)row2 * N_DIM + col] = v;
                        outb[(size_t)row2 * N_DIM + col] = __float2bfloat16(v);
                    }
                }
            }
        }
    }
}

// ---------------- MFMA flash attention: one block per (b, h) ----------------
// qkv row: [q(512)|k(512)|v(512)], head h at cols h*64..h*64+63.
// vtg[(b*8+h)][d][m] = V^T, written by the qkv GEMM epilogue (m<197 only; tail
// zero-guarded during staging here).

__global__ void __launch_bounds__(256, 2) attn_kernel(const hb* __restrict__ qkv,
                                                      const hb* __restrict__ vtg,
                                                      hb* __restrict__ ctx) {
    __shared__ hb Ks[224 * 64];      // K  [key][d]     28,672 B
    __shared__ hb Vt[64 * 224];      // V^T[d][key]     28,672 B
    __shared__ hb Pb[4][16 * 40];    // per-wave P bounce, stride 40 (16B-aligned rows)
    const int bh = blockIdx.x;
    const int b = bh >> 3, h = bh & 7;
    const int tid = threadIdx.x, lane = tid & 63, wid = tid >> 6;
    const int quad = lane >> 4, r16 = lane & 15;
    const hb* base = qkv + (size_t)(b * N_TOK) * 1536 + h * 64;
    const hb* vbase = vtg + (size_t)bh * (64 * 224);

    // stage K: rows m<197 from global, m>=197 zero
#pragma unroll
    for (int i = 0; i < 7; ++i) {
        int idx = tid + i * 256;               // 1792 16B chunks
        int m = idx >> 3, c = idx & 7;
        bf16x8 val = {};
        if (m < 197) val = *(const bf16x8*)(base + (size_t)m * 1536 + 512 + c * 8);
        *(bf16x8*)&Ks[m * 64 + c * 8] = val;
    }
    // stage V^T: m<192 vectorized from vtg; tail scalar with zero-pad
#pragma unroll
    for (int i = 0; i < 6; ++i) {
        int idx = tid + i * 256;               // 1536 16B chunks (64 d x 24 chunks)
        int d = idx / 24, mc = idx % 24;
        *(bf16x8*)&Vt[d * 224 + mc * 8] = *(const bf16x8*)(vbase + d * 224 + mc * 8);
    }
    const hb hzero = __float2bfloat16(0.f);
#pragma unroll
    for (int i = 0; i < 8; ++i) {
        int idx = tid + i * 256;               // 2048 scalars (64 d x 32 m)
        int d = idx >> 5, m = 192 + (idx & 31);
        Vt[d * 224 + m] = (m < 197) ? vbase[d * 224 + m] : hzero;
    }

    // Q fragments: 64 query rows per wave (rows wid*64 .. wid*64+63; pad rows >=197 garbage, unused)
    bf16x8 af[4][2];
#pragma unroll
    for (int mi = 0; mi < 4; ++mi) {
        int q = wid * 64 + mi * 16 + r16;
#pragma unroll
        for (int kc = 0; kc < 2; ++kc)
            af[mi][kc] = *(const bf16x8*)(base + (size_t)q * 1536 + kc * 32 + quad * 8);
    }

    f32x4 o[4][4] = {};
    float mst[4][4], lp[4][4];
#pragma unroll
    for (int mi = 0; mi < 4; ++mi)
#pragma unroll
        for (int e = 0; e < 4; ++e) { mst[mi][e] = -3.0e38f; lp[mi][e] = 0.f; }

    __syncthreads();

    for (int kt = 0; kt < 7; ++kt) {
        bf16x8 bk[2][2], bv[4];
#pragma unroll
        for (int nj = 0; nj < 2; ++nj)
#pragma unroll
            for (int kc = 0; kc < 2; ++kc)
                bk[nj][kc] = *(const bf16x8*)&Ks[(kt * 32 + nj * 16 + r16) * 64 + kc * 32 + quad * 8];
#pragma unroll
        for (int jd = 0; jd < 4; ++jd)
            bv[jd] = *(const bf16x8*)&Vt[(jd * 16 + r16) * 224 + kt * 32 + quad * 8];

        const bool v0 = (kt * 32 + r16) < N_TOK;
        const bool v1 = (kt * 32 + 16 + r16) < N_TOK;

#pragma unroll
        for (int mi = 0; mi < 4; ++mi) {
            f32x4 z = {};
            f32x4 s0v = __builtin_amdgcn_mfma_f32_16x16x32_bf16(af[mi][0], bk[0][0], z, 0, 0, 0);
            s0v = __builtin_amdgcn_mfma_f32_16x16x32_bf16(af[mi][1], bk[0][1], s0v, 0, 0, 0);
            f32x4 s1v = __builtin_amdgcn_mfma_f32_16x16x32_bf16(af[mi][0], bk[1][0], z, 0, 0, 0);
            s1v = __builtin_amdgcn_mfma_f32_16x16x32_bf16(af[mi][1], bk[1][1], s1v, 0, 0, 0);

            float al[4];
#pragma unroll
            for (int e = 0; e < 4; ++e) {
                float s0 = v0 ? s0v[e] * 0.125f : -1e30f;
                float s1 = v1 ? s1v[e] * 0.125f : -1e30f;
                float mx = fmaxf(s0, s1);
#pragma unroll
                for (int off = 1; off < 16; off <<= 1) mx = fmaxf(mx, __shfl_xor(mx, off));
                float mnew = fmaxf(mst[mi][e], mx);
                float alpha = __expf(mst[mi][e] - mnew);
                mst[mi][e] = mnew;
                float p0 = __expf(s0 - mnew);
                float p1 = __expf(s1 - mnew);
                // lane-partial l accumulation: reduced across the 16-lane group once, at the end
                lp[mi][e] = lp[mi][e] * alpha + p0 + p1;
                al[e] = alpha;
                int prow = (quad * 4 + e) * 40;
                Pb[wid][prow + r16]      = __float2bfloat16(p0);
                Pb[wid][prow + 16 + r16] = __float2bfloat16(p1);
            }
#pragma unroll
            for (int jd = 0; jd < 4; ++jd)
#pragma unroll
                for (int e = 0; e < 4; ++e) o[mi][jd][e] *= al[e];
            // C-layout -> A-layout transform via per-wave LDS bounce (wave-private: no barrier)
            bf16x8 ap = *(const bf16x8*)&Pb[wid][r16 * 40 + quad * 8];
#pragma unroll
            for (int jd = 0; jd < 4; ++jd)
                o[mi][jd] = __builtin_amdgcn_mfma_f32_16x16x32_bf16(ap, bv[jd], o[mi][jd], 0, 0, 0);
        }
    }

    // epilogue: final l reduction + normalized store
#pragma unroll
    for (int mi = 0; mi < 4; ++mi) {
        float rl[4];
#pragma unroll
        for (int e = 0; e < 4; ++e) {
            float l = lp[mi][e];
#pragma unroll
            for (int off = 1; off < 16; off <<= 1) l += __shfl_xor(l, off);
            rl[e] = 1.f / l;
        }
        int qrow = wid * 64 + mi * 16 + quad * 4;
#pragma unroll
        for (int e = 0; e < 4; ++e) {
            int q = qrow + e;
            if (q < N_TOK) {
                hb* dst = ctx + ((size_t)(b * N_TOK + q)) * N_DIM + h * 64;
#pragma unroll
                for (int jd = 0; jd < 4; ++jd)
                    dst[jd * 16 + r16] = __float2bfloat16(o[mi][jd][e] * rl[e]);
            }
        }
    }
}

// ---------------- launch ----------------

extern "C" void kernel_launch(void* const* d_in, const int* in_sizes, int n_in,
                              void* d_out, int out_size, void* d_ws, size_t ws_size,
                              hipStream_t stream) {
    (void)in_sizes; (void)n_in; (void)out_size; (void)ws_size;
    const float* img     = (const float*)d_in[0];
    const float* patch_w = (const float*)d_in[1];
    const float* patch_b = (const float*)d_in[2];
    const float* cls_t   = (const float*)d_in[3];
    const float* pos     = (const float*)d_in[4];
    const float* w_qkv   = (const float*)d_in[5];
    const float* b_qkv   = (const float*)d_in[6];
    const float* w_out   = (const float*)d_in[7];
    const float* b_out   = (const float*)d_in[8];
    const float* ln1w    = (const float*)d_in[9];
    const float* ln1b    = (const float*)d_in[10];
    const float* w_fc1   = (const float*)d_in[11];
    const float* b_fc1   = (const float*)d_in[12];
    const float* w_fc2   = (const float*)d_in[13];
    const float* b_fc2   = (const float*)d_in[14];
    const float* ln2w    = (const float*)d_in[15];
    const float* ln2b    = (const float*)d_in[16];

    char* ws = (char*)d_ws;
    hb* wPatch = (hb*)(ws + OFF_WPATCH);
    hb* wQKV   = (hb*)(ws + OFF_WQKV);
    hb* wOut   = (hb*)(ws + OFF_WOUT);
    hb* wFc1   = (hb*)(ws + OFF_WFC1);
    hb* wFc2   = (hb*)(ws + OFF_WFC2);
    hb* x_bf   = (hb*)(ws + OFF_XBF);
    hb* ctx    = (hb*)(ws + OFF_CTX);
    hb* Xp     = (hb*)(ws + OFF_BIG);
    hb* qkv    = (hb*)(ws + OFF_BIG);
    hb* hmid   = (hb*)(ws + OFF_BIG);
    float* x_f = (float*)(ws + OFF_XF);
    float* h1  = (float*)(ws + OFF_H1);
    hb* vtg    = (hb*)(ws + OFF_H1);   // aliases h1; lifetimes disjoint within a layer

    auto cvt = [&](const float* src, hb* dst, int n) {
        cvt_bf16_kernel<<<dim3((n + 255) / 256), dim3(256), 0, stream>>>(src, dst, n);
    };
    cvt(patch_w, wPatch, 512 * 768);
    cvt(w_qkv, wQKV, N_DEPTH * 1536 * 512);
    cvt(w_out, wOut, N_DEPTH * 512 * 512);
    cvt(w_fc1, wFc1, N_DEPTH * 2048 * 512);
    cvt(w_fc2, wFc2, N_DEPTH * 512 * 2048);

    patchify_kernel<<<dim3((PROWS * 768 + 255) / 256), dim3(256), 0, stream>>>(img, Xp);
    gemm_bt<3><<<dim3(4, 98), dim3(256), 0, stream>>>(Xp, wPatch, patch_b, 768, 512, x_bf, x_f, nullptr, pos, nullptr);
    cls_init_kernel<<<dim3(128), dim3(256), 0, stream>>>(cls_t, pos, x_f, x_bf);
    zero_pads_kernel<<<dim3(128), dim3(256), 0, stream>>>(x_f, x_bf, ctx);

    for (int i = 0; i < N_DEPTH; ++i) {
        gemm_bt<0><<<dim3(12, 99), dim3(256), 0, stream>>>(x_bf, wQKV + (size_t)i * 1536 * 512,
                                                           b_qkv + i * 1536, 512, 1536, qkv, nullptr, nullptr, nullptr, vtg);
        attn_kernel<<<dim3(512), dim3(256), 0, stream>>>(qkv, vtg, ctx);
        gemm_bt<2><<<dim3(4, 99), dim3(256), 0, stream>>>(ctx, wOut + (size_t)i * 512 * 512,
                                                          b_out + i * 512, 512, 512, nullptr, h1, x_f, nullptr, nullptr);
        ln_kernel<<<dim3(3152), dim3(256), 0, stream>>>(h1, ln1w + i * 512, ln1b + i * 512, x_f, x_bf, ROWS);
        gemm_bt<1><<<dim3(16, 99), dim3(256), 0, stream>>>(x_bf, wFc1 + (size_t)i * 2048 * 512,
                                                           b_fc1 + i * 2048, 512, 2048, hmid, nullptr, nullptr, nullptr, nullptr);
        gemm_bt<2><<<dim3(4, 99), dim3(256), 0, stream>>>(hmid, wFc2 + (size_t)i * 512 * 2048,
                                                          b_fc2 + i * 512, 2048, 512, nullptr, h1, x_f, nullptr, nullptr);
        ln_kernel<<<dim3(3152), dim3(256), 0, stream>>>(h1, ln2w + i * 512, ln2b + i * 512, x_f, x_bf, ROWS);
    }

    extract_cls_kernel<<<dim3(128), dim3(256), 0, stream>>>(x_f, (float*)d_out);
}